// Round 17
// baseline (374.624 us; speedup 1.0000x reference)
//
#include <hip/hip_runtime.h>
#include <hip/hip_bf16.h>
#include <math.h>

// AttentionDownSample: fm [8,128,256,256] f32, Wq/Wk [32,128] f32
// out [8,128,128,128] f32.
//
// r17: cheap t-algebra + bf16 LDS stash + ALL hot-loop operands in LDS.
//   - r16 showed the fused K-algebra is 3.5x the FMA and 4x redundant ->
//     back to t[c]=sum_r Q[r]Wk[r,c], logit_s=sum_c t[c]v_s[c] with v
//     stashed bf16 in LDS (read-fm-once stays).
//   - r4 lesson: weights must be ds_read too (no SMEM/DS lgkm mixing):
//     wbuf 8 KB staged 4x (Wq-lo/hi, Wk-lo/hi) via global_load_lds,
//     restages overlapped with Q atomics. r-split halves register need.
//   - LDS = stash 64K + wbuf 8K + Qbuf 8K (aliased lbuf/abuf) = 81920 B
//     EXACTLY -> 2 blocks/CU -> 256-VGPR allocator budget -> spill-proof
//     (r8/r9/r11/r13 all spilled when the budget was 64).
//   - 64-pos tiles (512 B contiguous per (c,row) — r7's 2.86 TB/s locality;
//     32/16-pos tiles measured 1.2/0.9 TB/s).
//   - ph1 is a PURE load->pack->ds_write stream (8-ch ring, no FMA trains).
//   - 2 resident blocks/CU at naturally offset phases: one block's ph1
//     stream overlaps the other's LDS-only GEMM phases -> HBM duty cycle.
// Math: u[c]=v0+v1+v2+v3 (recomputed from bf16 stash in ph2);
// Q[r]=sum_c WqT'[c][r]u[c] (0.25/sqrt32 folded); t[c]=sum_r Q[r]WkT[c][r];
// logit_s=sum_c t[c]v_s[c]; out[c]=sum_s softmax(logit)_s v_s[c].

typedef unsigned int uint32;
typedef const __attribute__((address_space(1))) void* gas_t;
typedef __attribute__((address_space(3))) void* las_t;

__device__ __forceinline__ uint32 pack2(float x, float y) {
  union { __hip_bfloat162 h; uint32 u; } cvt;
  cvt.h = __float22bfloat162_rn(make_float2(x, y));
  return cvt.u;
}
__device__ __forceinline__ float2 unpack2(uint32 u) {
  float2 r;
  r.x = __uint_as_float(u << 16);
  r.y = __uint_as_float(u & 0xffff0000u);
  return r;
}

// ws float layout (split for 8 KB half-staging):
// [0..2047]    WqT' lo  [c][r0..15]     [2048..4095] WqT' hi [c][r16..31]
// [4096..6143] WkT  lo  [c][r0..15]     [6144..8191] WkT  hi [c][r16..31]
__global__ __launch_bounds__(256) void wt_kernel(const float* __restrict__ Wq,
                                                 const float* __restrict__ Wk,
                                                 float* __restrict__ ws) {
  int t = blockIdx.x * 256 + threadIdx.x;
  if (t < 4096) {
    int c = t >> 5, r = t & 31;
    int half = r >> 4, rr = r & 15;
    ws[half * 2048 + c * 16 + rr] = Wq[r * 128 + c] * (0.25f / sqrtf(32.0f));
    ws[4096 + half * 2048 + c * 16 + rr] = Wk[r * 128 + c];
  }
}

__global__ __launch_bounds__(256)
void attn_main(const float* __restrict__ fm,
               const float* __restrict__ ws,
               float* __restrict__ out) {
  extern __shared__ char smem[];
  uint2* stash = (uint2*)smem;              // [128 c][64 p]  64 KB
  float* wbuf  = (float*)(smem + 65536);    // [128 c][16 r]   8 KB (4 stages)
  float* Qbuf  = (float*)(smem + 73728);    // [32 r][64 p]    8 KB
  float* lbuf  = Qbuf;                      // alias: [4 w][64 p][4 s]
  float* abuf  = Qbuf + 1024;               // alias: [64 p][4 s]

  const int tid = threadIdx.x;
  const int p   = tid & 63;                                  // position
  const int w   = __builtin_amdgcn_readfirstlane(tid >> 6);  // wave 0..3
  const int cb  = 32 * w;                                    // channel base

  const int blk = blockIdx.x;      // 2048 = 8 b * 128 h * 2 wt
  const int w0  = (blk & 1) * 64;
  const int h   = (blk >> 1) & 127;
  const int b   = blk >> 8;

  // zero Qbuf (before first barrier; atomics happen much later)
#pragma unroll
  for (int j = 0; j < 8; ++j) Qbuf[tid * 8 + j] = 0.f;

  // weight stage helper: 8 KB from ws+koff -> wbuf (2 x global_load_lds)
#define STAGE(koff)                                                          \
  {                                                                          \
    const char* src = (const char*)ws + (koff) + tid * 16;                   \
    char* dst = (char*)wbuf + tid * 16;                                      \
    __builtin_amdgcn_global_load_lds((gas_t)src, (las_t)dst, 16, 0, 0);      \
    __builtin_amdgcn_global_load_lds((gas_t)(src + 4096), (las_t)(dst + 4096),\
                                     16, 0, 0);                              \
  }

  STAGE(0)  // S0 = Wq-lo

  // ---- ph1: PURE stream — fm read once, pack bf16, ds_write stash ----
  {
    const float* g = fm + ((size_t)(b * 128 + cb)) * 65536 +
                     (size_t)(2 * h) * 256 + 2 * (w0 + p);
    float2 ra[8], rb[8];
#pragma unroll
    for (int i = 0; i < 8; ++i) {
      ra[i] = *(const float2*)(g + (size_t)i * 65536);
      rb[i] = *(const float2*)(g + (size_t)i * 65536 + 256);
    }
#pragma unroll
    for (int c0 = 0; c0 < 32; c0 += 8) {
#pragma unroll
      for (int j = 0; j < 8; ++j) {
        const float2 va = ra[j];
        const float2 vb = rb[j];
        if (c0 < 24) {
          ra[j] = *(const float2*)(g + (size_t)(c0 + 8 + j) * 65536);
          rb[j] = *(const float2*)(g + (size_t)(c0 + 8 + j) * 65536 + 256);
        }
        stash[(cb + c0 + j) * 64 + p] =
            make_uint2(pack2(va.x, va.y), pack2(vb.x, vb.y));
      }
    }
  }
  asm volatile("s_waitcnt vmcnt(0)" ::: "memory");  // S0 landed (own wave)
  __syncthreads();  // stash + wbuf(Wq-lo) + Qbuf zeros visible

  // ---- ph2a: Qacc[r0..15] over own 32 channels (all operands LDS) ----
  float Qacc[16];
#pragma unroll
  for (int r = 0; r < 16; ++r) Qacc[r] = 0.f;
#pragma unroll
  for (int c = 0; c < 32; ++c) {
    const int cc = cb + c;
    const uint2 sv = stash[cc * 64 + p];
    const float2 va = unpack2(sv.x);
    const float2 vb = unpack2(sv.y);
    const float u = (va.x + va.y) + (vb.x + vb.y);
    const float4 w0_ = *(const float4*)(wbuf + cc * 16 + 0);
    const float4 w1_ = *(const float4*)(wbuf + cc * 16 + 4);
    const float4 w2_ = *(const float4*)(wbuf + cc * 16 + 8);
    const float4 w3_ = *(const float4*)(wbuf + cc * 16 + 12);
    Qacc[0]  = fmaf(w0_.x, u, Qacc[0]);  Qacc[1]  = fmaf(w0_.y, u, Qacc[1]);
    Qacc[2]  = fmaf(w0_.z, u, Qacc[2]);  Qacc[3]  = fmaf(w0_.w, u, Qacc[3]);
    Qacc[4]  = fmaf(w1_.x, u, Qacc[4]);  Qacc[5]  = fmaf(w1_.y, u, Qacc[5]);
    Qacc[6]  = fmaf(w1_.z, u, Qacc[6]);  Qacc[7]  = fmaf(w1_.w, u, Qacc[7]);
    Qacc[8]  = fmaf(w2_.x, u, Qacc[8]);  Qacc[9]  = fmaf(w2_.y, u, Qacc[9]);
    Qacc[10] = fmaf(w2_.z, u, Qacc[10]); Qacc[11] = fmaf(w2_.w, u, Qacc[11]);
    Qacc[12] = fmaf(w3_.x, u, Qacc[12]); Qacc[13] = fmaf(w3_.y, u, Qacc[13]);
    Qacc[14] = fmaf(w3_.z, u, Qacc[14]); Qacc[15] = fmaf(w3_.w, u, Qacc[15]);
  }
  __syncthreads();  // all waves done reading Wq-lo
  STAGE(8192)       // S1 = Wq-hi (overlaps atomics)
#pragma unroll
  for (int r = 0; r < 16; ++r) atomicAdd(&Qbuf[r * 64 + p], Qacc[r]);
  asm volatile("s_waitcnt vmcnt(0)" ::: "memory");
  __syncthreads();  // wbuf = Wq-hi

  // ---- ph2b: Qacc[r16..31] ----
#pragma unroll
  for (int r = 0; r < 16; ++r) Qacc[r] = 0.f;
#pragma unroll
  for (int c = 0; c < 32; ++c) {
    const int cc = cb + c;
    const uint2 sv = stash[cc * 64 + p];
    const float2 va = unpack2(sv.x);
    const float2 vb = unpack2(sv.y);
    const float u = (va.x + va.y) + (vb.x + vb.y);
    const float4 w0_ = *(const float4*)(wbuf + cc * 16 + 0);
    const float4 w1_ = *(const float4*)(wbuf + cc * 16 + 4);
    const float4 w2_ = *(const float4*)(wbuf + cc * 16 + 8);
    const float4 w3_ = *(const float4*)(wbuf + cc * 16 + 12);
    Qacc[0]  = fmaf(w0_.x, u, Qacc[0]);  Qacc[1]  = fmaf(w0_.y, u, Qacc[1]);
    Qacc[2]  = fmaf(w0_.z, u, Qacc[2]);  Qacc[3]  = fmaf(w0_.w, u, Qacc[3]);
    Qacc[4]  = fmaf(w1_.x, u, Qacc[4]);  Qacc[5]  = fmaf(w1_.y, u, Qacc[5]);
    Qacc[6]  = fmaf(w1_.z, u, Qacc[6]);  Qacc[7]  = fmaf(w1_.w, u, Qacc[7]);
    Qacc[8]  = fmaf(w2_.x, u, Qacc[8]);  Qacc[9]  = fmaf(w2_.y, u, Qacc[9]);
    Qacc[10] = fmaf(w2_.z, u, Qacc[10]); Qacc[11] = fmaf(w2_.w, u, Qacc[11]);
    Qacc[12] = fmaf(w3_.x, u, Qacc[12]); Qacc[13] = fmaf(w3_.y, u, Qacc[13]);
    Qacc[14] = fmaf(w3_.z, u, Qacc[14]); Qacc[15] = fmaf(w3_.w, u, Qacc[15]);
  }
  __syncthreads();  // all waves done reading Wq-hi
  STAGE(16384)      // S2 = Wk-lo (overlaps atomics)
#pragma unroll
  for (int r = 0; r < 16; ++r) atomicAdd(&Qbuf[(16 + r) * 64 + p], Qacc[r]);
  asm volatile("s_waitcnt vmcnt(0)" ::: "memory");
  __syncthreads();  // wbuf = Wk-lo; ALL Q atomics complete

  // ---- qh: full Q for this position ----
  float qh[32];
#pragma unroll
  for (int r = 0; r < 32; ++r) qh[r] = Qbuf[r * 64 + p];

  // ---- ph3a: tpart[c] = sum_{r<16} qh[r] * Wk-lo[c][r] ----
  float tpart[32];
#pragma unroll
  for (int c = 0; c < 32; ++c) {
    const int cc = cb + c;
    const float4 k0 = *(const float4*)(wbuf + cc * 16 + 0);
    const float4 k1 = *(const float4*)(wbuf + cc * 16 + 4);
    const float4 k2 = *(const float4*)(wbuf + cc * 16 + 8);
    const float4 k3 = *(const float4*)(wbuf + cc * 16 + 12);
    float t0 = qh[0] * k0.x, t1 = qh[1] * k0.y;
    t0 = fmaf(qh[2],  k0.z, t0); t1 = fmaf(qh[3],  k0.w, t1);
    t0 = fmaf(qh[4],  k1.x, t0); t1 = fmaf(qh[5],  k1.y, t1);
    t0 = fmaf(qh[6],  k1.z, t0); t1 = fmaf(qh[7],  k1.w, t1);
    t0 = fmaf(qh[8],  k2.x, t0); t1 = fmaf(qh[9],  k2.y, t1);
    t0 = fmaf(qh[10], k2.z, t0); t1 = fmaf(qh[11], k2.w, t1);
    t0 = fmaf(qh[12], k3.x, t0); t1 = fmaf(qh[13], k3.y, t1);
    t0 = fmaf(qh[14], k3.z, t0); t1 = fmaf(qh[15], k3.w, t1);
    tpart[c] = t0 + t1;
  }
  __syncthreads();  // done reading Wk-lo
  STAGE(24576)      // S3 = Wk-hi
  asm volatile("s_waitcnt vmcnt(0)" ::: "memory");
  __syncthreads();  // wbuf = Wk-hi

  // ---- ph3b: finish t, accumulate logits from stash ----
  float l0 = 0.f, l1 = 0.f, l2 = 0.f, l3 = 0.f;
#pragma unroll
  for (int c = 0; c < 32; ++c) {
    const int cc = cb + c;
    const float4 k0 = *(const float4*)(wbuf + cc * 16 + 0);
    const float4 k1 = *(const float4*)(wbuf + cc * 16 + 4);
    const float4 k2 = *(const float4*)(wbuf + cc * 16 + 8);
    const float4 k3 = *(const float4*)(wbuf + cc * 16 + 12);
    float t0 = qh[16] * k0.x, t1 = qh[17] * k0.y;
    t0 = fmaf(qh[18], k0.z, t0); t1 = fmaf(qh[19], k0.w, t1);
    t0 = fmaf(qh[20], k1.x, t0); t1 = fmaf(qh[21], k1.y, t1);
    t0 = fmaf(qh[22], k1.z, t0); t1 = fmaf(qh[23], k1.w, t1);
    t0 = fmaf(qh[24], k2.x, t0); t1 = fmaf(qh[25], k2.y, t1);
    t0 = fmaf(qh[26], k2.z, t0); t1 = fmaf(qh[27], k2.w, t1);
    t0 = fmaf(qh[28], k3.x, t0); t1 = fmaf(qh[29], k3.y, t1);
    t0 = fmaf(qh[30], k3.z, t0); t1 = fmaf(qh[31], k3.w, t1);
    const float tv = tpart[c] + (t0 + t1);
    const uint2 sv = stash[cc * 64 + p];
    const float2 va = unpack2(sv.x);
    const float2 vb = unpack2(sv.y);
    l0 = fmaf(tv, va.x, l0);
    l1 = fmaf(tv, va.y, l1);
    l2 = fmaf(tv, vb.x, l2);
    l3 = fmaf(tv, vb.y, l3);
  }
  __syncthreads();  // qh reads long done; Qbuf region now reusable as lbuf
  *(float4*)(lbuf + (w * 64 + p) * 4) = make_float4(l0, l1, l2, l3);
  __syncthreads();

  // ---- softmax (one wave combines the 4 partials, broadcasts) ----
  if (tid < 64) {
    const float4 s0 = *(const float4*)(lbuf + (0 * 64 + tid) * 4);
    const float4 s1 = *(const float4*)(lbuf + (1 * 64 + tid) * 4);
    const float4 s2 = *(const float4*)(lbuf + (2 * 64 + tid) * 4);
    const float4 s3 = *(const float4*)(lbuf + (3 * 64 + tid) * 4);
    const float L0 = (s0.x + s1.x) + (s2.x + s3.x);
    const float L1 = (s0.y + s1.y) + (s2.y + s3.y);
    const float L2 = (s0.z + s1.z) + (s2.z + s3.z);
    const float L3 = (s0.w + s1.w) + (s2.w + s3.w);
    const float mx = fmaxf(fmaxf(L0, L1), fmaxf(L2, L3));
    const float e0 = __expf(L0 - mx), e1 = __expf(L1 - mx);
    const float e2 = __expf(L2 - mx), e3 = __expf(L3 - mx);
    const float inv = 1.0f / ((e0 + e1) + (e2 + e3));
    *(float4*)(abuf + tid * 4) =
        make_float4(e0 * inv, e1 * inv, e2 * inv, e3 * inv);
  }
  __syncthreads();

  // ---- apply: out[c] = sum_s attn_s * v_s (from stash, coalesced) ----
  {
    const float4 at = *(const float4*)(abuf + p * 4);
    float* op = out + ((size_t)(b * 128 + cb)) * 16384 + h * 128 + w0 + p;
#pragma unroll 8
    for (int c = 0; c < 32; ++c) {
      const uint2 sv = stash[(cb + c) * 64 + p];
      const float2 va = unpack2(sv.x);
      const float2 vb = unpack2(sv.y);
      op[(size_t)c * 16384] =
          fmaf(at.x, va.x, fmaf(at.y, va.y, fmaf(at.z, vb.x, at.w * vb.y)));
    }
  }
#undef STAGE
}

extern "C" void kernel_launch(void* const* d_in, const int* in_sizes, int n_in,
                              void* d_out, int out_size, void* d_ws, size_t ws_size,
                              hipStream_t stream) {
  const float* fm = (const float*)d_in[0];
  const float* Wq = (const float*)d_in[1];
  const float* Wk = (const float*)d_in[2];
  float* outp = (float*)d_out;
  float* ws = (float*)d_ws;

  const int smem_bytes = 81920;  // 64K stash + 8K wbuf + 8K Qbuf = 2 blocks/CU
  (void)hipFuncSetAttribute((const void*)attn_main,
                            hipFuncAttributeMaxDynamicSharedMemorySize,
                            smem_bytes);

  wt_kernel<<<16, 256, 0, stream>>>(Wq, Wk, ws);
  attn_main<<<2048, 256, smem_bytes, stream>>>(fm, ws, outp);
}

// Round 18
// 204.260 us; speedup vs baseline: 1.8341x; 1.8341x over previous
//
#include <hip/hip_runtime.h>
#include <hip/hip_bf16.h>
#include <math.h>

// AttentionDownSample: fm [8,128,256,256] f32, Wq/Wk [32,128] f32
// out [8,128,128,128] f32.
//
// r18 = r17 architecture with the three execution bugs fixed:
//   r17 failed with VGPR=256 + 240 MB scratch: fully-unrolled hot loops let
//   the scheduler pipeline ds_reads past any register budget.
//   (a) __launch_bounds__(256,4): hard 128-reg budget (need ~90-110).
//   (b) #pragma unroll 4 everywhere hot: bounded live ranges.
//   (c) weights stored PACKED BF16 -> whole Wq (or Wk) = 8 KB in wbuf at
//       once: no r-halves, no tpart[32], 2 fewer stage/barrier rounds.
// LDS = stash 64K (v bf16x2 [128c][64p]) + wbuf 8K (WqP then WkP) +
//       Qbuf 8K f32 (aliased by lbuf/abuf after qh read) = 81920 B exactly
//       -> 2 blocks/CU. 64-position tiles (512 B contiguous chunks, r7's
//       proven DRAM locality). ph1 = pure stream; 2 resident blocks at
//       offset phases cover each other's droughts.
// Math: u[c]=v0+v1+v2+v3 (f32 from stash); Q[r]=sum_c WqT'[c][r]u[c]
// (0.25/sqrt32 folded); t[c]=sum_r Q[r]WkT[c][r]; logit_s=sum_c t[c]v_s[c];
// out[c]=sum_s softmax(logit)_s v_s[c]. Weights bf16 (~0.4% rel, ok).

typedef unsigned int uint32;
typedef const __attribute__((address_space(1))) void* gas_t;
typedef __attribute__((address_space(3))) void* las_t;

__device__ __forceinline__ uint32 pack2(float x, float y) {
  union { __hip_bfloat162 h; uint32 u; } cvt;
  cvt.h = __float22bfloat162_rn(make_float2(x, y));
  return cvt.u;
}
__device__ __forceinline__ float2 unpack2(uint32 u) {
  float2 r;
  r.x = __uint_as_float(u << 16);
  r.y = __uint_as_float(u & 0xffff0000u);
  return r;
}

// ws as uint32: [0..2047] WqP[c][16] (bf16 pairs r=2j,2j+1, scale folded)
//               [2048..4095] WkP[c][16]
__global__ __launch_bounds__(256) void wt_kernel(const float* __restrict__ Wq,
                                                 const float* __restrict__ Wk,
                                                 uint32* __restrict__ ws) {
  int t = blockIdx.x * 256 + threadIdx.x;  // 2048 threads, one (c,j) each
  if (t < 2048) {
    int c = t >> 4, j = t & 15;
    const float s = 0.25f / sqrtf(32.0f);
    ws[c * 16 + j] = pack2(Wq[(2 * j) * 128 + c] * s,
                           Wq[(2 * j + 1) * 128 + c] * s);
    ws[2048 + c * 16 + j] = pack2(Wk[(2 * j) * 128 + c],
                                  Wk[(2 * j + 1) * 128 + c]);
  }
}

__global__ __launch_bounds__(256, 4)
void attn_main(const float* __restrict__ fm,
               const uint32* __restrict__ ws,
               float* __restrict__ out) {
  extern __shared__ char smem[];
  uint2*  stash = (uint2*)smem;             // [128 c][64 p]   64 KB
  uint32* wbuf  = (uint32*)(smem + 65536);  // [128 c][16 j]    8 KB
  float*  Qbuf  = (float*)(smem + 73728);   // [32 r][64 p]     8 KB
  float*  lbuf  = Qbuf;                     // alias: [4 w][64 p][4 s]
  float*  abuf  = Qbuf + 1024;              // alias: [64 p][4 s]

  const int tid = threadIdx.x;
  const int p   = tid & 63;                                  // position
  const int w   = __builtin_amdgcn_readfirstlane(tid >> 6);  // wave 0..3
  const int cb  = 32 * w;                                    // channel base

  const int blk = blockIdx.x;      // 2048 = 8 b * 128 h * 2 wt
  const int w0  = (blk & 1) * 64;
  const int h   = (blk >> 1) & 127;
  const int b   = blk >> 8;

  // zero Qbuf (2048 floats / 256 thr = 8 each), before first barrier
#pragma unroll
  for (int j = 0; j < 8; ++j) Qbuf[tid * 8 + j] = 0.f;

  // stage WqP (8 KB = 2 x 16B/thread issues)
  {
    const char* src = (const char*)ws + tid * 16;
    char* dst = (char*)wbuf + tid * 16;
    __builtin_amdgcn_global_load_lds((gas_t)src, (las_t)dst, 16, 0, 0);
    __builtin_amdgcn_global_load_lds((gas_t)(src + 4096), (las_t)(dst + 4096),
                                     16, 0, 0);
  }

  // ---- ph1: PURE stream — fm read once, pack bf16, ds_write stash ----
  {
    const float* g = fm + ((size_t)(b * 128 + cb)) * 65536 +
                     (size_t)(2 * h) * 256 + 2 * (w0 + p);
#pragma unroll 8
    for (int c = 0; c < 32; ++c) {
      const float2 va = *(const float2*)(g + (size_t)c * 65536);        // row0
      const float2 vb = *(const float2*)(g + (size_t)c * 65536 + 256);  // row1
      stash[(cb + c) * 64 + p] =
          make_uint2(pack2(va.x, va.y), pack2(vb.x, vb.y));
    }
  }
  asm volatile("s_waitcnt vmcnt(0)" ::: "memory");
  __syncthreads();  // stash + wbuf(WqP) + Qbuf zeros visible

#define QFMA(word, r0)                              \
  {                                                 \
    const float2 f = unpack2(word);                 \
    Qacc[r0] = fmaf(f.x, u, Qacc[r0]);              \
    Qacc[(r0) + 1] = fmaf(f.y, u, Qacc[(r0) + 1]);  \
  }

  // ---- ph2: Qacc[0..31] over own 32 channels (all operands LDS) ----
  float Qacc[32];
#pragma unroll
  for (int r = 0; r < 32; ++r) Qacc[r] = 0.f;
#pragma unroll 4
  for (int c = 0; c < 32; ++c) {
    const int cc = cb + c;
    const uint2 sv = stash[cc * 64 + p];
    const float2 va = unpack2(sv.x);
    const float2 vb = unpack2(sv.y);
    const float u = (va.x + va.y) + (vb.x + vb.y);
    const uint4 wa = *(const uint4*)(wbuf + cc * 16);
    const uint4 wb = *(const uint4*)(wbuf + cc * 16 + 4);
    const uint4 wc = *(const uint4*)(wbuf + cc * 16 + 8);
    const uint4 wd = *(const uint4*)(wbuf + cc * 16 + 12);
    QFMA(wa.x, 0)  QFMA(wa.y, 2)  QFMA(wa.z, 4)  QFMA(wa.w, 6)
    QFMA(wb.x, 8)  QFMA(wb.y, 10) QFMA(wb.z, 12) QFMA(wb.w, 14)
    QFMA(wc.x, 16) QFMA(wc.y, 18) QFMA(wc.z, 20) QFMA(wc.w, 22)
    QFMA(wd.x, 24) QFMA(wd.y, 26) QFMA(wd.z, 28) QFMA(wd.w, 30)
  }
#undef QFMA
  __syncthreads();  // all waves done reading WqP

  // restage wbuf = WkP (overlaps the Q atomics below)
  {
    const char* src = (const char*)ws + 8192 + tid * 16;
    char* dst = (char*)wbuf + tid * 16;
    __builtin_amdgcn_global_load_lds((gas_t)src, (las_t)dst, 16, 0, 0);
    __builtin_amdgcn_global_load_lds((gas_t)(src + 4096), (las_t)(dst + 4096),
                                     16, 0, 0);
  }
#pragma unroll 8
  for (int r = 0; r < 32; ++r) atomicAdd(&Qbuf[r * 64 + p], Qacc[r]);
  asm volatile("s_waitcnt vmcnt(0)" ::: "memory");
  __syncthreads();  // wbuf = WkP; Q complete

  // ---- qh: full Q for this position (then barrier before lbuf alias) ----
  float qh[32];
#pragma unroll
  for (int r = 0; r < 32; ++r) qh[r] = Qbuf[r * 64 + p];
  __syncthreads();  // every wave has its qh -> Qbuf reusable as lbuf

#define TFMA(word, r0)                      \
  {                                         \
    const float2 f = unpack2(word);         \
    t0 = fmaf(qh[r0], f.x, t0);             \
    t1 = fmaf(qh[(r0) + 1], f.y, t1);       \
  }

  // ---- ph3: t[c] + logits from stash ----
  float l0 = 0.f, l1 = 0.f, l2 = 0.f, l3 = 0.f;
#pragma unroll 4
  for (int c = 0; c < 32; ++c) {
    const int cc = cb + c;
    const uint4 wa = *(const uint4*)(wbuf + cc * 16);
    const uint4 wb = *(const uint4*)(wbuf + cc * 16 + 4);
    const uint4 wc = *(const uint4*)(wbuf + cc * 16 + 8);
    const uint4 wd = *(const uint4*)(wbuf + cc * 16 + 12);
    float t0 = 0.f, t1 = 0.f;
    TFMA(wa.x, 0)  TFMA(wa.y, 2)  TFMA(wa.z, 4)  TFMA(wa.w, 6)
    TFMA(wb.x, 8)  TFMA(wb.y, 10) TFMA(wb.z, 12) TFMA(wb.w, 14)
    TFMA(wc.x, 16) TFMA(wc.y, 18) TFMA(wc.z, 20) TFMA(wc.w, 22)
    TFMA(wd.x, 24) TFMA(wd.y, 26) TFMA(wd.z, 28) TFMA(wd.w, 30)
    const float tv = t0 + t1;
    const uint2 sv = stash[cc * 64 + p];
    const float2 va = unpack2(sv.x);
    const float2 vb = unpack2(sv.y);
    l0 = fmaf(tv, va.x, l0);
    l1 = fmaf(tv, va.y, l1);
    l2 = fmaf(tv, vb.x, l2);
    l3 = fmaf(tv, vb.y, l3);
  }
#undef TFMA
  *(float4*)(lbuf + (w * 64 + p) * 4) = make_float4(l0, l1, l2, l3);
  __syncthreads();

  // ---- softmax (one wave combines 4 partials, broadcasts via abuf) ----
  if (tid < 64) {
    const float4 s0 = *(const float4*)(lbuf + (0 * 64 + tid) * 4);
    const float4 s1 = *(const float4*)(lbuf + (1 * 64 + tid) * 4);
    const float4 s2 = *(const float4*)(lbuf + (2 * 64 + tid) * 4);
    const float4 s3 = *(const float4*)(lbuf + (3 * 64 + tid) * 4);
    const float L0 = (s0.x + s1.x) + (s2.x + s3.x);
    const float L1 = (s0.y + s1.y) + (s2.y + s3.y);
    const float L2 = (s0.z + s1.z) + (s2.z + s3.z);
    const float L3 = (s0.w + s1.w) + (s2.w + s3.w);
    const float mx = fmaxf(fmaxf(L0, L1), fmaxf(L2, L3));
    const float e0 = __expf(L0 - mx), e1 = __expf(L1 - mx);
    const float e2 = __expf(L2 - mx), e3 = __expf(L3 - mx);
    const float inv = 1.0f / ((e0 + e1) + (e2 + e3));
    *(float4*)(abuf + tid * 4) =
        make_float4(e0 * inv, e1 * inv, e2 * inv, e3 * inv);
  }
  __syncthreads();

  // ---- apply: out[c] = sum_s attn_s * v_s (from stash, coalesced) ----
  {
    const float4 at = *(const float4*)(abuf + p * 4);
    float* op = out + ((size_t)(b * 128 + cb)) * 16384 + h * 128 + w0 + p;
#pragma unroll 4
    for (int c = 0; c < 32; ++c) {
      const uint2 sv = stash[(cb + c) * 64 + p];
      const float2 va = unpack2(sv.x);
      const float2 vb = unpack2(sv.y);
      op[(size_t)c * 16384] =
          fmaf(at.x, va.x, fmaf(at.y, va.y, fmaf(at.z, vb.x, at.w * vb.y)));
    }
  }
}

extern "C" void kernel_launch(void* const* d_in, const int* in_sizes, int n_in,
                              void* d_out, int out_size, void* d_ws, size_t ws_size,
                              hipStream_t stream) {
  const float* fm = (const float*)d_in[0];
  const float* Wq = (const float*)d_in[1];
  const float* Wk = (const float*)d_in[2];
  float* outp = (float*)d_out;
  uint32* ws = (uint32*)d_ws;

  const int smem_bytes = 81920;  // 64K stash + 8K wbuf + 8K Qbuf = 2 blocks/CU
  (void)hipFuncSetAttribute((const void*)attn_main,
                            hipFuncAttributeMaxDynamicSharedMemorySize,
                            smem_bytes);

  wt_kernel<<<8, 256, 0, stream>>>(Wq, Wk, ws);
  attn_main<<<2048, 256, smem_bytes, stream>>>(fm, ws, outp);
}